// Round 6
// baseline (2556.295 us; speedup 1.0000x reference)
//
#include <hip/hip_runtime.h>
#include <stdint.h>

#define H   300
#define HP  320
#define CAP 32     // max incoming bonds per atom (Binomial(400k,1/200k) max ~13)

using bf8 = __attribute__((ext_vector_type(8))) short;   // 8 x bf16
using f4  = __attribute__((ext_vector_type(4))) float;   // MFMA acc

__device__ __forceinline__ float bf2f(unsigned short u){
    union { unsigned int i; float f; } v; v.i = ((unsigned int)u) << 16; return v.f;
}
__device__ __forceinline__ unsigned short f2bf(float x){
    unsigned int u = __builtin_bit_cast(unsigned int, x);
    u = (u + 0x7FFFu + ((u >> 16) & 1u)) >> 16;   // RNE
    return (unsigned short)u;
}

// ---------------------------------------------------------------------------
// Incoming-bond bucket list: bucket[a][0..cnt[a]) = bond indices with dst==a
// ---------------------------------------------------------------------------
__global__ void fill_k(const int* __restrict__ b_dst, int* __restrict__ cnt,
                       int* __restrict__ bucket, int nB){
    int e = blockIdx.x * 256 + threadIdx.x;
    if (e >= nB) return;
    int d = b_dst[e];
    int slot = atomicAdd(&cnt[d], 1);
    if (slot < CAP) bucket[(long)d * CAP + slot] = e;
}

// ---------------------------------------------------------------------------
// Weight prep: W [Kact][H] fp32 -> Wt [320][Kp] bf16, transposed + zero-padded
// ---------------------------------------------------------------------------
__global__ void prep_wt(const float* __restrict__ W, unsigned short* __restrict__ Wt,
                        int Kact, int Kp){
    int idx = blockIdx.x * 256 + threadIdx.x;
    if (idx >= 320 * Kp) return;
    int n = idx / Kp, k = idx % Kp;
    float v = (n < H && k < Kact) ? W[(long)k * H + n] : 0.f;
    Wt[idx] = f2bf(v);
}

// W_o [900][300] -> Wt_o [320][960]: k = sec*320+kk maps to W row sec*300+kk
__global__ void prep_wto(const float* __restrict__ W, unsigned short* __restrict__ Wt){
    int idx = blockIdx.x * 256 + threadIdx.x;
    if (idx >= 320 * 960) return;
    int n = idx / 960, k = idx % 960;
    int blk = k / HP, kk = k % HP;
    float v = (n < H && kk < H) ? W[((long)blk * H + kk) * H + n] : 0.f;
    Wt[idx] = f2bf(v);
}

// ---------------------------------------------------------------------------
// Input feature conversion: X fp32 [rows][Kact] -> Y bf16 [rows][160] padded
// ---------------------------------------------------------------------------
__global__ __launch_bounds__(256)
void conv_in(const float* __restrict__ X, int rows, int Kact,
             unsigned short* __restrict__ Y){
    int t = blockIdx.x * 256 + threadIdx.x;
    if (t >= rows * 20) return;
    int row = t / 20, k0 = (t % 20) * 8;
    bf8 v;
    #pragma unroll
    for (int j = 0; j < 8; j++){
        int k = k0 + j;
        float f = (k < Kact) ? X[(long)row * Kact + k] : 0.f;
        v[j] = (short)f2bf(f);
    }
    *(bf8*)(Y + (long)row * 160 + k0) = v;
}

// ---------------------------------------------------------------------------
// Persistent pipelined GEMM: out[rows][320] = epi( [A0|A1|A2][rows][SEC*RL] @ Wt^T )
// A-tile (64 x RL bf16) DMA'd via global_load_lds into double-buffered LDS;
// next unit's DMA overlaps current unit's K-loop (m97 structure).
// Swizzle: linear LDS dest + inverse-swizzled global src + swizzled ds_read.
// B: depth-3 register pipeline from L2-resident weights. Grid-stride tiles.
// EPI: 0 = relu, 1 = raw, 2 = relu + b_o
// ---------------------------------------------------------------------------
template<int RL, int SEC, int EPI>
__global__ __launch_bounds__(256, 2)
void gemm_p(const unsigned short* __restrict__ A0,
            const unsigned short* __restrict__ A1,
            const unsigned short* __restrict__ A2,
            const unsigned short* __restrict__ Wt,   // [320][SEC*RL]
            const float* __restrict__ b_o,
            unsigned short* __restrict__ outb,       // [rows][320]
            int nTiles)
{
    constexpr int KS     = RL / 32;        // K-steps per section
    constexpr int CHUNKS = RL / 8;         // 16B chunks per row
    constexpr int XM     = (CHUNKS == 40) ? 7 : 3;
    constexpr int TILEB  = 64 * RL * 2;    // bytes per LDS buffer
    constexpr int ROUNDS = TILEB / 4096;   // 256 thr x 16B per round
    constexpr int Ktot   = SEC * RL;

    __shared__ char lds[2 * TILEB];

    const int tid  = threadIdx.x;
    const int w    = tid >> 6;
    const int lane = tid & 63;
    const int lr   = lane & 15;
    const int g    = lane >> 4;

    const unsigned short* Ap[3] = {A0, A1, A2};

    auto dma = [&](const unsigned short* src, int rowBase, int buf){
        const char* gbase = (const char*)(src + (long)rowBase * RL);
        char* lbase = lds + buf * TILEB + (w * 64) * 16;
        #pragma unroll
        for (int rd = 0; rd < ROUNDS; rd++){
            int f   = rd * 256 + tid;
            int row = f / CHUNKS;
            int c   = f - row * CHUNKS;
            int cs  = c ^ (row & XM);              // inverse swizzle on source
            const char* gp = gbase + ((long)row * CHUNKS + cs) * 16;
            __builtin_amdgcn_global_load_lds(
                (const __attribute__((address_space(1))) void*)gp,
                (__attribute__((address_space(3))) void*)(lbase + rd * 4096),
                16, 0, 0);
        }
    };

    auto aoff = [&](int buf, int row, int chunk)->int {
        return buf * TILEB + row * (RL * 2) + ((chunk ^ (row & XM)) << 4);
    };

    bf8 bb[3][5];
    auto loadB = [&](int ks, int slot){
        #pragma unroll
        for (int n = 0; n < 5; n++)
            bb[slot][n] = *(const bf8*)(Wt + (long)(w * 80 + n * 16 + lr) * Ktot + ks * 32 + g * 8);
    };

    f4 acc[4][5];

    int tile = blockIdx.x;
    if (tile >= nTiles) return;
    dma(Ap[0], tile * 64, 0);
    __syncthreads();                       // drain prologue DMA

    int buf = 0;
    for (; tile < nTiles; tile += gridDim.x){
        #pragma unroll
        for (int m = 0; m < 4; m++)
            #pragma unroll
            for (int n = 0; n < 5; n++)
                acc[m][n] = (f4){0.f, 0.f, 0.f, 0.f};

        #pragma unroll
        for (int sec = 0; sec < SEC; ++sec){
            // issue next unit's DMA into the other buffer (overlaps compute)
            {
                int ns = sec + 1, ntile = tile;
                if (ns == SEC){ ns = 0; ntile = tile + (int)gridDim.x; }
                if (ntile < nTiles) dma(Ap[ns], ntile * 64, buf ^ 1);
            }
            loadB(sec * KS + 0, 0);
            loadB(sec * KS + 1, 1);
            loadB(sec * KS + 2, 2);

            #pragma unroll
            for (int i = 0; i < KS; i++){
                bf8 af[4];
                #pragma unroll
                for (int m = 0; m < 4; m++)
                    af[m] = *(const bf8*)(lds + aoff(buf, m * 16 + lr, i * 4 + g));
                #pragma unroll
                for (int m = 0; m < 4; m++)
                    #pragma unroll
                    for (int n = 0; n < 5; n++)
                        acc[m][n] = __builtin_amdgcn_mfma_f32_16x16x32_bf16(af[m], bb[i % 3][n], acc[m][n], 0, 0, 0);
                if (i + 3 < KS) loadB(sec * KS + i + 3, i % 3);
            }

            if (sec == SEC - 1){
                const int rgrp = g * 4;
                #pragma unroll
                for (int m = 0; m < 4; m++){
                    #pragma unroll
                    for (int n = 0; n < 5; n++){
                        int col = w * 80 + n * 16 + lr;
                        #pragma unroll
                        for (int q = 0; q < 4; q++){
                            int gr = tile * 64 + m * 16 + rgrp + q;
                            float v = acc[m][n][q];
                            if constexpr (EPI == 2) v += (col < H ? b_o[col] : 0.f);
                            if constexpr (EPI != 1) v = fmaxf(v, 0.f);
                            outb[(long)gr * HP + col] = f2bf(v);
                        }
                    }
                }
            }
            __syncthreads();               // drain DMA(next) + LDS-read fence
            buf ^= 1;
        }
    }
}

// ---------------------------------------------------------------------------
// comb: msg'[e] = relu(bond_in[e] + sum_{j in bucket[src[e]]} MW[j] - MW[rev[e]])
// thread = (bond, 8-col chunk); 16B loads, 6 independent loads in flight.
// ---------------------------------------------------------------------------
__global__ __launch_bounds__(256)
void comb_k(const unsigned short* __restrict__ MW,
            const unsigned short* __restrict__ bond_in,
            const int* __restrict__ b_src, const int* __restrict__ b2revb,
            const int* __restrict__ cnt, const int* __restrict__ bucket,
            unsigned short* __restrict__ out, int nB){
    int t = blockIdx.x * 256 + threadIdx.x;
    if (t >= nB * 40) return;
    int e = t / 40, ch = t % 40;
    int k0 = ch * 8;
    int s   = b_src[e];
    int rev = b2revb[e];
    int dg = cnt[s]; if (dg > CAP) dg = CAP;
    long base = (long)s * CAP;
    int be0 = 0, be1 = 0, be2 = 0, be3 = 0;
    if (dg > 0) be0 = bucket[base + 0];
    if (dg > 1) be1 = bucket[base + 1];
    if (dg > 2) be2 = bucket[base + 2];
    if (dg > 3) be3 = bucket[base + 3];
    bf8 bi = *(const bf8*)(bond_in + (long)e * HP + k0);
    bf8 rv = *(const bf8*)(MW + (long)rev * HP + k0);
    bf8 m0, m1, m2, m3;
    if (dg > 0) m0 = *(const bf8*)(MW + (long)be0 * HP + k0);
    if (dg > 1) m1 = *(const bf8*)(MW + (long)be1 * HP + k0);
    if (dg > 2) m2 = *(const bf8*)(MW + (long)be2 * HP + k0);
    if (dg > 3) m3 = *(const bf8*)(MW + (long)be3 * HP + k0);
    float sacc[8];
    #pragma unroll
    for (int q = 0; q < 8; q++)
        sacc[q] = bf2f((unsigned short)bi[q]) - bf2f((unsigned short)rv[q]);
    auto addv = [&](bf8 mm){
        #pragma unroll
        for (int q = 0; q < 8; q++) sacc[q] += bf2f((unsigned short)mm[q]);
    };
    if (dg > 0) addv(m0);
    if (dg > 1) addv(m1);
    if (dg > 2) addv(m2);
    if (dg > 3) addv(m3);
    for (int j = 4; j < dg; ++j){
        int be = bucket[base + j];
        addv(*(const bf8*)(MW + (long)be * HP + k0));
    }
    bf8 v;
    #pragma unroll
    for (int q = 0; q < 8; q++) v[q] = (short)f2bf(fmaxf(sacc[q], 0.f));
    *(bf8*)(out + (long)e * HP + k0) = v;
}

// ---------------------------------------------------------------------------
// a_msg[a] = sum of msg rows with dst==a; also prod[a] = a_msg[a] * input_atom[a]
// ---------------------------------------------------------------------------
__global__ __launch_bounds__(256)
void amsg_k(const unsigned short* __restrict__ msg, const int* __restrict__ cnt,
            const int* __restrict__ bucket,
            const unsigned short* __restrict__ input_atom,
            unsigned short* __restrict__ amsg, unsigned short* __restrict__ prod,
            int nA){
    int t = blockIdx.x * 256 + threadIdx.x;
    if (t >= nA * 40) return;
    int a = t / 40, ch = t % 40;
    int k0 = ch * 8;
    int dg = cnt[a]; if (dg > CAP) dg = CAP;
    long base = (long)a * CAP;
    int be0 = 0, be1 = 0, be2 = 0, be3 = 0;
    if (dg > 0) be0 = bucket[base + 0];
    if (dg > 1) be1 = bucket[base + 1];
    if (dg > 2) be2 = bucket[base + 2];
    if (dg > 3) be3 = bucket[base + 3];
    bf8 ia = *(const bf8*)(input_atom + (long)a * HP + k0);
    bf8 m0, m1, m2, m3;
    if (dg > 0) m0 = *(const bf8*)(msg + (long)be0 * HP + k0);
    if (dg > 1) m1 = *(const bf8*)(msg + (long)be1 * HP + k0);
    if (dg > 2) m2 = *(const bf8*)(msg + (long)be2 * HP + k0);
    if (dg > 3) m3 = *(const bf8*)(msg + (long)be3 * HP + k0);
    float s[8];
    #pragma unroll
    for (int q = 0; q < 8; q++) s[q] = 0.f;
    auto addv = [&](bf8 mm){
        #pragma unroll
        for (int q = 0; q < 8; q++) s[q] += bf2f((unsigned short)mm[q]);
    };
    if (dg > 0) addv(m0);
    if (dg > 1) addv(m1);
    if (dg > 2) addv(m2);
    if (dg > 3) addv(m3);
    for (int j = 4; j < dg; ++j)
        addv(*(const bf8*)(msg + (long)bucket[base + j] * HP + k0));
    bf8 va, vp;
    #pragma unroll
    for (int q = 0; q < 8; q++){
        va[q] = (short)f2bf(s[q]);
        vp[q] = (short)f2bf(s[q] * bf2f((unsigned short)ia[q]));
    }
    *(bf8*)(amsg + (long)a * HP + k0) = va;
    *(bf8*)(prod + (long)a * HP + k0) = vp;
}

// ---------------------------------------------------------------------------
// Readout: per-molecule mean over sorted mol_ids (binary-search range)
// ---------------------------------------------------------------------------
__global__ __launch_bounds__(320)
void readout_k(const unsigned short* __restrict__ atom_h,
               const int* __restrict__ mol_ids, int nAtoms,
               float* __restrict__ out){
    int m = blockIdx.x;
    int t = threadIdx.x;
    int lo = 0, hi = nAtoms;
    while (lo < hi){ int mid = (lo + hi) >> 1; if (mol_ids[mid] < m) lo = mid + 1; else hi = mid; }
    int lo2 = lo, hi2 = nAtoms;
    while (lo2 < hi2){ int mid = (lo2 + hi2) >> 1; if (mol_ids[mid] < m + 1) lo2 = mid + 1; else hi2 = mid; }
    if (t < H){
        float s = 0.f;
        for (int a = lo; a < lo2; ++a) s += bf2f(atom_h[(long)a * HP + t]);
        int c2 = lo2 - lo;
        out[(long)m * H + t] = s / (float)(c2 > 0 ? c2 : 1);
    }
}

// ---------------------------------------------------------------------------
extern "C" void kernel_launch(void* const* d_in, const int* in_sizes, int n_in,
                              void* d_out, int out_size, void* d_ws, size_t ws_size,
                              hipStream_t stream){
    const float* f_atoms  = (const float*)d_in[0];
    const float* f_bonds  = (const float*)d_in[1];
    const float* W_i_atom = (const float*)d_in[2];
    const float* W_i_bond = (const float*)d_in[3];
    const float* W_h      = (const float*)d_in[4];
    const float* W_o      = (const float*)d_in[5];
    const float* b_o      = (const float*)d_in[6];
    const int* b_src   = (const int*)d_in[7];
    const int* b_dst   = (const int*)d_in[8];
    const int* b2revb  = (const int*)d_in[9];
    const int* mol_ids = (const int*)d_in[10];

    const int nA = in_sizes[10];          // 200000
    const int nB = in_sizes[7];           // 400000
    const int nM = out_size / H;          // 4096

    char* p = (char*)d_ws;
    auto alloc = [&](size_t bytes){ char* q = p; p += (bytes + 255) & ~(size_t)255; return q; };
    unsigned short* Wt_ia = (unsigned short*)alloc((size_t)320 * 160 * 2);
    unsigned short* Wt_ib = (unsigned short*)alloc((size_t)320 * 160 * 2);
    unsigned short* Wt_h  = (unsigned short*)alloc((size_t)3 * 320 * 320 * 2);
    unsigned short* Wt_o  = (unsigned short*)alloc((size_t)320 * 960 * 2);
    int* cnt    = (int*)alloc((size_t)nA * 4);
    int* bucket = (int*)alloc((size_t)nA * CAP * 4);
    unsigned short* input_atom = (unsigned short*)alloc((size_t)nA * HP * 2);
    unsigned short* input_bond = (unsigned short*)alloc((size_t)nB * HP * 2);
    unsigned short* msgA = (unsigned short*)alloc((size_t)nB * HP * 2);
    unsigned short* MW   = (unsigned short*)alloc((size_t)nB * HP * 2);
    // aliases into dead regions:
    unsigned short* fa_bf  = MW;                                  // [nA][160] = 64 MB, dead before MW first written
    unsigned short* fb_bf  = MW + (size_t)nA * 160;               // [nB][160] = 128 MB
    unsigned short* amsg   = MW;                                  // MW dead after comb3
    unsigned short* prod   = MW + (size_t)nA * HP;                // 128 MB
    unsigned short* atom_h = input_bond;                          // dead after comb3

    if ((size_t)(p - (char*)d_ws) > ws_size) return;  // diagnostic: ws too small

    // adjacency buckets
    hipMemsetAsync(cnt, 0, (size_t)nA * 4, stream);
    fill_k<<<dim3((nB + 255) / 256), dim3(256), 0, stream>>>(b_dst, cnt, bucket, nB);

    // weight prep + input conversion
    prep_wt<<<dim3((320*160 + 255)/256), dim3(256), 0, stream>>>(W_i_atom, Wt_ia, 133, 160);
    prep_wt<<<dim3((320*160 + 255)/256), dim3(256), 0, stream>>>(W_i_bond, Wt_ib, 147, 160);
    for (int d = 0; d < 3; d++)
        prep_wt<<<dim3((320*320 + 255)/256), dim3(256), 0, stream>>>(
            W_h + (size_t)d * H * H, Wt_h + (size_t)d * 320 * 320, 300, 320);
    prep_wto<<<dim3((320*960 + 255)/256), dim3(256), 0, stream>>>(W_o, Wt_o);
    conv_in<<<dim3((nA*20 + 255)/256), dim3(256), 0, stream>>>(f_atoms, nA, 133, fa_bf);
    conv_in<<<dim3((nB*20 + 255)/256), dim3(256), 0, stream>>>(f_bonds, nB, 147, fb_bf);

    const int tilesA = nA / 64, tilesB = nB / 64;

    // input projections
    gemm_p<160,1,0><<<dim3(1024), dim3(256), 0, stream>>>(
        fa_bf, nullptr, nullptr, Wt_ia, nullptr, input_atom, tilesA);
    gemm_p<160,1,0><<<dim3(1024), dim3(256), 0, stream>>>(
        fb_bf, nullptr, nullptr, Wt_ib, nullptr, input_bond, tilesB);

    // message steps: MW = msg @ W_h[d]; msg' = relu(bond_in + bucket-sum - rev)
    const int combGrid = (nB * 40 + 255) / 256;
    const unsigned short* msg_cur = input_bond;
    for (int d = 0; d < 3; d++){
        gemm_p<320,1,1><<<dim3(512), dim3(256), 0, stream>>>(
            msg_cur, nullptr, nullptr, Wt_h + (size_t)d * 320 * 320, nullptr, MW, tilesB);
        comb_k<<<dim3(combGrid), dim3(256), 0, stream>>>(
            MW, input_bond, b_src, b2revb, cnt, bucket, msgA, nB);
        msg_cur = msgA;
    }

    // final per-atom aggregation + product (bf16)
    amsg_k<<<dim3((nA * 40 + 255) / 256), dim3(256), 0, stream>>>(
        msgA, cnt, bucket, input_atom, amsg, prod, nA);

    // atom_h = relu([input_atom | amsg | input_atom*amsg] @ W_o + b_o)
    gemm_p<320,3,2><<<dim3(512), dim3(256), 0, stream>>>(
        input_atom, amsg, prod, Wt_o, b_o, atom_h, tilesA);

    // per-molecule mean
    readout_k<<<dim3(nM), dim3(320), 0, stream>>>(atom_h, mol_ids, nA, (float*)d_out);
}

// Round 7
// 2286.509 us; speedup vs baseline: 1.1180x; 1.1180x over previous
//
#include <hip/hip_runtime.h>
#include <stdint.h>

#define H   300
#define HP  320
#define CAP 32     // max incoming bonds per atom (Binomial(400k,1/200k) max ~13)

using bf8 = __attribute__((ext_vector_type(8))) short;   // 8 x bf16
using f4  = __attribute__((ext_vector_type(4))) float;   // MFMA acc

__device__ __forceinline__ float bf2f(unsigned short u){
    union { unsigned int i; float f; } v; v.i = ((unsigned int)u) << 16; return v.f;
}
__device__ __forceinline__ unsigned short f2bf(float x){
    unsigned int u = __builtin_bit_cast(unsigned int, x);
    u = (u + 0x7FFFu + ((u >> 16) & 1u)) >> 16;   // RNE
    return (unsigned short)u;
}

// Swizzled row layout: element (row,col) of a [rows][320] buffer lives at
//   row*320 + ((col>>3) ^ (row&7))*8 + (col&7)
// (involution within each 8-chunk group; rows are 128B-group permuted).
// For [rows][160] buffers the mask is row&3 (20 chunks = 5 groups of 4).
__device__ __forceinline__ long sidx320(long row, int ch){
    return row * HP + ((long)(ch ^ ((int)row & 7)) << 3);
}

// ---------------------------------------------------------------------------
// Incoming-bond bucket list: bucket[a][0..cnt[a]) = bond indices with dst==a
// ---------------------------------------------------------------------------
__global__ void fill_k(const int* __restrict__ b_dst, int* __restrict__ cnt,
                       int* __restrict__ bucket, int nB){
    int e = blockIdx.x * 256 + threadIdx.x;
    if (e >= nB) return;
    int d = b_dst[e];
    int slot = atomicAdd(&cnt[d], 1);
    if (slot < CAP) bucket[(long)d * CAP + slot] = e;
}

// ---------------------------------------------------------------------------
// Weight prep: W [Kact][H] fp32 -> Wt [320][Kp] bf16, transposed + zero-padded
// (linear layout; weights are read via plain loads, not DMA)
// ---------------------------------------------------------------------------
__global__ void prep_wt(const float* __restrict__ W, unsigned short* __restrict__ Wt,
                        int Kact, int Kp){
    int idx = blockIdx.x * 256 + threadIdx.x;
    if (idx >= 320 * Kp) return;
    int n = idx / Kp, k = idx % Kp;
    float v = (n < H && k < Kact) ? W[(long)k * H + n] : 0.f;
    Wt[idx] = f2bf(v);
}

// W_o [900][300] -> Wt_o [320][960]: k = sec*320+kk maps to W row sec*300+kk
__global__ void prep_wto(const float* __restrict__ W, unsigned short* __restrict__ Wt){
    int idx = blockIdx.x * 256 + threadIdx.x;
    if (idx >= 320 * 960) return;
    int n = idx / 960, k = idx % 960;
    int blk = k / HP, kk = k % HP;
    float v = (n < H && kk < H) ? W[((long)blk * H + kk) * H + n] : 0.f;
    Wt[idx] = f2bf(v);
}

// ---------------------------------------------------------------------------
// Input feature conversion: X fp32 [rows][Kact] -> Y bf16 [rows][160] padded,
// written PRE-SWIZZLED (chunk ^ (row&3)) so GEMM DMA reads are contiguous.
// ---------------------------------------------------------------------------
__global__ __launch_bounds__(256)
void conv_in(const float* __restrict__ X, int rows, int Kact,
             unsigned short* __restrict__ Y){
    int t = blockIdx.x * 256 + threadIdx.x;
    if (t >= rows * 20) return;
    int row = t / 20, c = t % 20;
    int k0 = c * 8;
    bf8 v;
    #pragma unroll
    for (int j = 0; j < 8; j++){
        int k = k0 + j;
        float f = (k < Kact) ? X[(long)row * Kact + k] : 0.f;
        v[j] = (short)f2bf(f);
    }
    *(bf8*)(Y + (long)row * 160 + ((c ^ (row & 3)) << 3)) = v;
}

// ---------------------------------------------------------------------------
// Persistent pipelined GEMM: out[rows][320] = epi( [A0|A1|A2][rows][SEC*RL] @ Wt^T )
// A-tiles pre-swizzled in memory -> DMA source is CONTIGUOUS (1KiB/wave/instr),
// LDS linear copy, ds_read applies the XOR. NT hint (aux=2) keeps weights in L2.
// B: depth-3 register pipeline from L2-resident weights. Grid-stride tiles.
// EPI: 0 = relu, 1 = raw, 2 = relu + b_o.  Output written pre-swizzled.
// ---------------------------------------------------------------------------
template<int RL, int SEC, int EPI>
__global__ __launch_bounds__(256, 2)
void gemm_p(const unsigned short* __restrict__ A0,
            const unsigned short* __restrict__ A1,
            const unsigned short* __restrict__ A2,
            const unsigned short* __restrict__ Wt,   // [320][SEC*RL]
            const float* __restrict__ b_o,
            unsigned short* __restrict__ outb,       // [rows][320] swizzled
            int nTiles)
{
    constexpr int KS     = RL / 32;        // K-steps per section
    constexpr int XM     = (RL == 320) ? 7 : 3;
    constexpr int TILEB  = 64 * RL * 2;    // bytes per LDS buffer
    constexpr int ROUNDS = TILEB / 4096;   // 256 thr x 16B per round
    constexpr int Ktot   = SEC * RL;

    __shared__ char lds[2 * TILEB];

    const int tid  = threadIdx.x;
    const int w    = tid >> 6;
    const int lane = tid & 63;
    const int lr   = lane & 15;
    const int g    = lane >> 4;

    const unsigned short* Ap[3] = {A0, A1, A2};

    auto dma = [&](const unsigned short* src, int rowBase, int buf){
        const char* g0 = (const char*)(src + (long)rowBase * RL) + tid * 16;
        char* l0 = lds + buf * TILEB + (w * 64) * 16;   // wave-uniform base
        #pragma unroll
        for (int rd = 0; rd < ROUNDS; rd++){
            __builtin_amdgcn_global_load_lds(
                (const __attribute__((address_space(1))) void*)(g0 + rd * 4096),
                (__attribute__((address_space(3))) void*)(l0 + rd * 4096),
                16, 0, 2 /* NT: don't pollute L2/L3 with single-use A stream */);
        }
    };

    auto aoff = [&](int buf, int row, int chunk)->int {
        return buf * TILEB + row * (RL * 2) + (((chunk) ^ (row & XM)) << 4);
    };

    bf8 bb[3][5];
    auto loadB = [&](int ks, int slot){
        #pragma unroll
        for (int n = 0; n < 5; n++)
            bb[slot][n] = *(const bf8*)(Wt + (long)(w * 80 + n * 16 + lr) * Ktot + ks * 32 + g * 8);
    };

    f4 acc[4][5];

    int tile = blockIdx.x;
    if (tile >= nTiles) return;
    dma(Ap[0], tile * 64, 0);
    __syncthreads();                       // drain prologue DMA

    int buf = 0;
    for (; tile < nTiles; tile += gridDim.x){
        #pragma unroll
        for (int m = 0; m < 4; m++)
            #pragma unroll
            for (int n = 0; n < 5; n++)
                acc[m][n] = (f4){0.f, 0.f, 0.f, 0.f};

        #pragma unroll
        for (int sec = 0; sec < SEC; ++sec){
            // issue next unit's DMA into the other buffer (overlaps compute)
            {
                int ns = sec + 1, ntile = tile;
                if (ns == SEC){ ns = 0; ntile = tile + (int)gridDim.x; }
                if (ntile < nTiles) dma(Ap[ns], ntile * 64, buf ^ 1);
            }
            loadB(sec * KS + 0, 0);
            loadB(sec * KS + 1, 1);
            loadB(sec * KS + 2, 2);

            #pragma unroll
            for (int i = 0; i < KS; i++){
                bf8 af[4];
                #pragma unroll
                for (int m = 0; m < 4; m++)
                    af[m] = *(const bf8*)(lds + aoff(buf, m * 16 + lr, i * 4 + g));
                #pragma unroll
                for (int m = 0; m < 4; m++)
                    #pragma unroll
                    for (int n = 0; n < 5; n++)
                        acc[m][n] = __builtin_amdgcn_mfma_f32_16x16x32_bf16(af[m], bb[i % 3][n], acc[m][n], 0, 0, 0);
                if (i + 3 < KS) loadB(sec * KS + i + 3, i % 3);
            }

            if (sec == SEC - 1){
                const int rgrp = g * 4;
                #pragma unroll
                for (int m = 0; m < 4; m++){
                    #pragma unroll
                    for (int n = 0; n < 5; n++){
                        int col = w * 80 + n * 16 + lr;
                        #pragma unroll
                        for (int q = 0; q < 4; q++){
                            int gr = tile * 64 + m * 16 + rgrp + q;
                            float v = acc[m][n][q];
                            if constexpr (EPI == 2) v += (col < H ? b_o[col] : 0.f);
                            if constexpr (EPI != 1) v = fmaxf(v, 0.f);
                            outb[(long)gr * HP + (((col >> 3) ^ (gr & 7)) << 3) + (col & 7)] = f2bf(v);
                        }
                    }
                }
            }
            __syncthreads();               // drain DMA(next) + LDS-read fence
            buf ^= 1;
        }
    }
}

// ---------------------------------------------------------------------------
// comb: msg'[e] = relu(bond_in[e] + sum_{j in bucket[src[e]]} MW[j] - MW[rev[e]])
// thread = (bond, 16B chunk); all buffers in swizzled layout.
// ---------------------------------------------------------------------------
__global__ __launch_bounds__(256)
void comb_k(const unsigned short* __restrict__ MW,
            const unsigned short* __restrict__ bond_in,
            const int* __restrict__ b_src, const int* __restrict__ b2revb,
            const int* __restrict__ cnt, const int* __restrict__ bucket,
            unsigned short* __restrict__ out, int nB){
    int t = blockIdx.x * 256 + threadIdx.x;
    if (t >= nB * 40) return;
    int e = t / 40, ch = t % 40;
    int s   = b_src[e];
    int rev = b2revb[e];
    int dg = cnt[s]; if (dg > CAP) dg = CAP;
    long base = (long)s * CAP;
    int be0 = 0, be1 = 0, be2 = 0, be3 = 0;
    if (dg > 0) be0 = bucket[base + 0];
    if (dg > 1) be1 = bucket[base + 1];
    if (dg > 2) be2 = bucket[base + 2];
    if (dg > 3) be3 = bucket[base + 3];
    bf8 bi = *(const bf8*)(bond_in + sidx320(e, ch));
    bf8 rv = *(const bf8*)(MW + sidx320(rev, ch));
    bf8 m0, m1, m2, m3;
    if (dg > 0) m0 = *(const bf8*)(MW + sidx320(be0, ch));
    if (dg > 1) m1 = *(const bf8*)(MW + sidx320(be1, ch));
    if (dg > 2) m2 = *(const bf8*)(MW + sidx320(be2, ch));
    if (dg > 3) m3 = *(const bf8*)(MW + sidx320(be3, ch));
    float sacc[8];
    #pragma unroll
    for (int q = 0; q < 8; q++)
        sacc[q] = bf2f((unsigned short)bi[q]) - bf2f((unsigned short)rv[q]);
    auto addv = [&](bf8 mm){
        #pragma unroll
        for (int q = 0; q < 8; q++) sacc[q] += bf2f((unsigned short)mm[q]);
    };
    if (dg > 0) addv(m0);
    if (dg > 1) addv(m1);
    if (dg > 2) addv(m2);
    if (dg > 3) addv(m3);
    for (int j = 4; j < dg; ++j){
        int be = bucket[base + j];
        addv(*(const bf8*)(MW + sidx320(be, ch)));
    }
    bf8 v;
    #pragma unroll
    for (int q = 0; q < 8; q++) v[q] = (short)f2bf(fmaxf(sacc[q], 0.f));
    *(bf8*)(out + sidx320(e, ch)) = v;
}

// ---------------------------------------------------------------------------
// a_msg[a] = sum of msg rows with dst==a; also prod[a] = a_msg[a] * input_atom[a]
// (all swizzled layout)
// ---------------------------------------------------------------------------
__global__ __launch_bounds__(256)
void amsg_k(const unsigned short* __restrict__ msg, const int* __restrict__ cnt,
            const int* __restrict__ bucket,
            const unsigned short* __restrict__ input_atom,
            unsigned short* __restrict__ amsg, unsigned short* __restrict__ prod,
            int nA){
    int t = blockIdx.x * 256 + threadIdx.x;
    if (t >= nA * 40) return;
    int a = t / 40, ch = t % 40;
    int dg = cnt[a]; if (dg > CAP) dg = CAP;
    long base = (long)a * CAP;
    int be0 = 0, be1 = 0, be2 = 0, be3 = 0;
    if (dg > 0) be0 = bucket[base + 0];
    if (dg > 1) be1 = bucket[base + 1];
    if (dg > 2) be2 = bucket[base + 2];
    if (dg > 3) be3 = bucket[base + 3];
    bf8 ia = *(const bf8*)(input_atom + sidx320(a, ch));
    bf8 m0, m1, m2, m3;
    if (dg > 0) m0 = *(const bf8*)(msg + sidx320(be0, ch));
    if (dg > 1) m1 = *(const bf8*)(msg + sidx320(be1, ch));
    if (dg > 2) m2 = *(const bf8*)(msg + sidx320(be2, ch));
    if (dg > 3) m3 = *(const bf8*)(msg + sidx320(be3, ch));
    float s[8];
    #pragma unroll
    for (int q = 0; q < 8; q++) s[q] = 0.f;
    auto addv = [&](bf8 mm){
        #pragma unroll
        for (int q = 0; q < 8; q++) s[q] += bf2f((unsigned short)mm[q]);
    };
    if (dg > 0) addv(m0);
    if (dg > 1) addv(m1);
    if (dg > 2) addv(m2);
    if (dg > 3) addv(m3);
    for (int j = 4; j < dg; ++j)
        addv(*(const bf8*)(msg + sidx320(bucket[base + j], ch)));
    bf8 va, vp;
    #pragma unroll
    for (int q = 0; q < 8; q++){
        va[q] = (short)f2bf(s[q]);
        vp[q] = (short)f2bf(s[q] * bf2f((unsigned short)ia[q]));
    }
    *(bf8*)(amsg + sidx320(a, ch)) = va;
    *(bf8*)(prod + sidx320(a, ch)) = vp;
}

// ---------------------------------------------------------------------------
// Readout: per-molecule mean over sorted mol_ids (binary-search range).
// atom_h is in swizzled layout; output d_out is linear.
// ---------------------------------------------------------------------------
__global__ __launch_bounds__(320)
void readout_k(const unsigned short* __restrict__ atom_h,
               const int* __restrict__ mol_ids, int nAtoms,
               float* __restrict__ out){
    int m = blockIdx.x;
    int t = threadIdx.x;
    int lo = 0, hi = nAtoms;
    while (lo < hi){ int mid = (lo + hi) >> 1; if (mol_ids[mid] < m) lo = mid + 1; else hi = mid; }
    int lo2 = lo, hi2 = nAtoms;
    while (lo2 < hi2){ int mid = (lo2 + hi2) >> 1; if (mol_ids[mid] < m + 1) lo2 = mid + 1; else hi2 = mid; }
    if (t < H){
        int ch = t >> 3, j = t & 7;
        float s = 0.f;
        for (int a = lo; a < lo2; ++a)
            s += bf2f(atom_h[sidx320(a, ch) + j]);
        int c2 = lo2 - lo;
        out[(long)m * H + t] = s / (float)(c2 > 0 ? c2 : 1);
    }
}

// ---------------------------------------------------------------------------
extern "C" void kernel_launch(void* const* d_in, const int* in_sizes, int n_in,
                              void* d_out, int out_size, void* d_ws, size_t ws_size,
                              hipStream_t stream){
    const float* f_atoms  = (const float*)d_in[0];
    const float* f_bonds  = (const float*)d_in[1];
    const float* W_i_atom = (const float*)d_in[2];
    const float* W_i_bond = (const float*)d_in[3];
    const float* W_h      = (const float*)d_in[4];
    const float* W_o      = (const float*)d_in[5];
    const float* b_o      = (const float*)d_in[6];
    const int* b_src   = (const int*)d_in[7];
    const int* b_dst   = (const int*)d_in[8];
    const int* b2revb  = (const int*)d_in[9];
    const int* mol_ids = (const int*)d_in[10];

    const int nA = in_sizes[10];          // 200000
    const int nB = in_sizes[7];           // 400000
    const int nM = out_size / H;          // 4096

    char* p = (char*)d_ws;
    auto alloc = [&](size_t bytes){ char* q = p; p += (bytes + 255) & ~(size_t)255; return q; };
    unsigned short* Wt_ia = (unsigned short*)alloc((size_t)320 * 160 * 2);
    unsigned short* Wt_ib = (unsigned short*)alloc((size_t)320 * 160 * 2);
    unsigned short* Wt_h  = (unsigned short*)alloc((size_t)3 * 320 * 320 * 2);
    unsigned short* Wt_o  = (unsigned short*)alloc((size_t)320 * 960 * 2);
    int* cnt    = (int*)alloc((size_t)nA * 4);
    int* bucket = (int*)alloc((size_t)nA * CAP * 4);
    unsigned short* input_atom = (unsigned short*)alloc((size_t)nA * HP * 2);
    unsigned short* input_bond = (unsigned short*)alloc((size_t)nB * HP * 2);
    unsigned short* msgA = (unsigned short*)alloc((size_t)nB * HP * 2);
    unsigned short* MW   = (unsigned short*)alloc((size_t)nB * HP * 2);
    // aliases into dead regions:
    unsigned short* fa_bf  = MW;                                  // [nA][160], dead before MW first written
    unsigned short* fb_bf  = MW + (size_t)nA * 160;               // [nB][160]
    unsigned short* amsg   = MW;                                  // MW dead after comb3
    unsigned short* prod   = MW + (size_t)nA * HP;
    unsigned short* atom_h = input_bond;                          // dead after comb3

    if ((size_t)(p - (char*)d_ws) > ws_size) return;  // diagnostic: ws too small

    // adjacency buckets
    hipMemsetAsync(cnt, 0, (size_t)nA * 4, stream);
    fill_k<<<dim3((nB + 255) / 256), dim3(256), 0, stream>>>(b_dst, cnt, bucket, nB);

    // weight prep + input conversion (inputs pre-swizzled)
    prep_wt<<<dim3((320*160 + 255)/256), dim3(256), 0, stream>>>(W_i_atom, Wt_ia, 133, 160);
    prep_wt<<<dim3((320*160 + 255)/256), dim3(256), 0, stream>>>(W_i_bond, Wt_ib, 147, 160);
    for (int d = 0; d < 3; d++)
        prep_wt<<<dim3((320*320 + 255)/256), dim3(256), 0, stream>>>(
            W_h + (size_t)d * H * H, Wt_h + (size_t)d * 320 * 320, 300, 320);
    prep_wto<<<dim3((320*960 + 255)/256), dim3(256), 0, stream>>>(W_o, Wt_o);
    conv_in<<<dim3((nA*20 + 255)/256), dim3(256), 0, stream>>>(f_atoms, nA, 133, fa_bf);
    conv_in<<<dim3((nB*20 + 255)/256), dim3(256), 0, stream>>>(f_bonds, nB, 147, fb_bf);

    const int tilesA = nA / 64, tilesB = nB / 64;

    // input projections
    gemm_p<160,1,0><<<dim3(1024), dim3(256), 0, stream>>>(
        fa_bf, nullptr, nullptr, Wt_ia, nullptr, input_atom, tilesA);
    gemm_p<160,1,0><<<dim3(1024), dim3(256), 0, stream>>>(
        fb_bf, nullptr, nullptr, Wt_ib, nullptr, input_bond, tilesB);

    // message steps: MW = msg @ W_h[d]; msg' = relu(bond_in + bucket-sum - rev)
    const int combGrid = (nB * 40 + 255) / 256;
    const unsigned short* msg_cur = input_bond;
    for (int d = 0; d < 3; d++){
        gemm_p<320,1,1><<<dim3(512), dim3(256), 0, stream>>>(
            msg_cur, nullptr, nullptr, Wt_h + (size_t)d * 320 * 320, nullptr, MW, tilesB);
        comb_k<<<dim3(combGrid), dim3(256), 0, stream>>>(
            MW, input_bond, b_src, b2revb, cnt, bucket, msgA, nB);
        msg_cur = msgA;
    }

    // final per-atom aggregation + product (bf16, swizzled)
    amsg_k<<<dim3((nA * 40 + 255) / 256), dim3(256), 0, stream>>>(
        msgA, cnt, bucket, input_atom, amsg, prod, nA);

    // atom_h = relu([input_atom | amsg | input_atom*amsg] @ W_o + b_o)
    gemm_p<320,3,2><<<dim3(512), dim3(256), 0, stream>>>(
        input_atom, amsg, prod, Wt_o, b_o, atom_h, tilesA);

    // per-molecule mean
    readout_k<<<dim3(nM), dim3(320), 0, stream>>>(atom_h, mol_ids, nA, (float*)d_out);
}

// Round 8
// 2284.867 us; speedup vs baseline: 1.1188x; 1.0007x over previous
//
#include <hip/hip_runtime.h>
#include <stdint.h>

#define H   300
#define HP  320
#define CAP 32     // max incoming bonds per atom (Binomial(400k,1/200k) max ~13)

using bf8 = __attribute__((ext_vector_type(8))) short;   // 8 x bf16
using s4  = __attribute__((ext_vector_type(4))) short;   // 4 x bf16 (8B store)
using f4  = __attribute__((ext_vector_type(4))) float;   // MFMA acc

__device__ __forceinline__ float bf2f(unsigned short u){
    union { unsigned int i; float f; } v; v.i = ((unsigned int)u) << 16; return v.f;
}
__device__ __forceinline__ unsigned short f2bf(float x){
    unsigned int u = __builtin_bit_cast(unsigned int, x);
    u = (u + 0x7FFFu + ((u >> 16) & 1u)) >> 16;   // RNE
    return (unsigned short)u;
}

// Swizzled row layout: element (row,col) of a [rows][320] buffer lives at
//   row*320 + ((col>>3) ^ (row&7))*8 + (col&7)
// For [rows][160] buffers the mask is row&3.
__device__ __forceinline__ long sidx320(long row, int ch){
    return row * HP + ((long)(ch ^ ((int)row & 7)) << 3);
}

// ---------------------------------------------------------------------------
// Incoming-bond bucket list: bucket[a][0..cnt[a]) = bond indices with dst==a
// ---------------------------------------------------------------------------
__global__ void fill_k(const int* __restrict__ b_dst, int* __restrict__ cnt,
                       int* __restrict__ bucket, int nB){
    int e = blockIdx.x * 256 + threadIdx.x;
    if (e >= nB) return;
    int d = b_dst[e];
    int slot = atomicAdd(&cnt[d], 1);
    if (slot < CAP) bucket[(long)d * CAP + slot] = e;
}

// ---------------------------------------------------------------------------
// Weight prep: W [Kact][H] fp32 -> Wt [320][Kp] bf16, transposed + zero-padded
// ---------------------------------------------------------------------------
__global__ void prep_wt(const float* __restrict__ W, unsigned short* __restrict__ Wt,
                        int Kact, int Kp){
    int idx = blockIdx.x * 256 + threadIdx.x;
    if (idx >= 320 * Kp) return;
    int n = idx / Kp, k = idx % Kp;
    float v = (n < H && k < Kact) ? W[(long)k * H + n] : 0.f;
    Wt[idx] = f2bf(v);
}

// W_o [900][300] -> Wt_o [320][960]: k = sec*320+kk maps to W row sec*300+kk
__global__ void prep_wto(const float* __restrict__ W, unsigned short* __restrict__ Wt){
    int idx = blockIdx.x * 256 + threadIdx.x;
    if (idx >= 320 * 960) return;
    int n = idx / 960, k = idx % 960;
    int blk = k / HP, kk = k % HP;
    float v = (n < H && kk < H) ? W[((long)blk * H + kk) * H + n] : 0.f;
    Wt[idx] = f2bf(v);
}

// ---------------------------------------------------------------------------
// Input feature conversion: X fp32 [rows][Kact] -> Y bf16 [rows][160] padded,
// written PRE-SWIZZLED (chunk ^ (row&3)) so GEMM DMA reads are contiguous.
// ---------------------------------------------------------------------------
__global__ __launch_bounds__(256)
void conv_in(const float* __restrict__ X, int rows, int Kact,
             unsigned short* __restrict__ Y){
    int t = blockIdx.x * 256 + threadIdx.x;
    if (t >= rows * 20) return;
    int row = t / 20, c = t % 20;
    int k0 = c * 8;
    bf8 v;
    #pragma unroll
    for (int j = 0; j < 8; j++){
        int k = k0 + j;
        float f = (k < Kact) ? X[(long)row * Kact + k] : 0.f;
        v[j] = (short)f2bf(f);
    }
    *(bf8*)(Y + (long)row * 160 + ((c ^ (row & 3)) << 3)) = v;
}

// ---------------------------------------------------------------------------
// Persistent pipelined GEMM: out[rows][320] = epi( [A0|A1|A2][rows][SEC*RL] @ Wt^T )
// A-tiles pre-swizzled -> DMA source contiguous; NT hint on the A stream.
// B: depth-3 register pipeline from L2-resident weights. Grid-stride tiles.
// MFMA operands SWAPPED (computes D^T): each lane holds 4 consecutive output
// cols of one row -> 8B contiguous epilogue stores (dense 64B-line fill).
// EPI: 0 = relu, 1 = raw, 2 = relu + b_o.  Output written pre-swizzled.
// ---------------------------------------------------------------------------
template<int RL, int SEC, int EPI>
__global__ __launch_bounds__(256, 2)
void gemm_p(const unsigned short* __restrict__ A0,
            const unsigned short* __restrict__ A1,
            const unsigned short* __restrict__ A2,
            const unsigned short* __restrict__ Wt,   // [320][SEC*RL]
            const float* __restrict__ b_o,
            unsigned short* __restrict__ outb,       // [rows][320] swizzled
            int nTiles)
{
    constexpr int KS     = RL / 32;        // K-steps per section
    constexpr int XM     = (RL == 320) ? 7 : 3;
    constexpr int TILEB  = 64 * RL * 2;    // bytes per LDS buffer
    constexpr int ROUNDS = TILEB / 4096;   // 256 thr x 16B per round
    constexpr int Ktot   = SEC * RL;

    __shared__ char lds[2 * TILEB];

    const int tid  = threadIdx.x;
    const int w    = tid >> 6;
    const int lane = tid & 63;
    const int lr   = lane & 15;
    const int g    = lane >> 4;

    const unsigned short* Ap[3] = {A0, A1, A2};

    auto dma = [&](const unsigned short* src, int rowBase, int buf){
        const char* g0 = (const char*)(src + (long)rowBase * RL) + tid * 16;
        char* l0 = lds + buf * TILEB + (w * 64) * 16;   // wave-uniform base
        #pragma unroll
        for (int rd = 0; rd < ROUNDS; rd++){
            __builtin_amdgcn_global_load_lds(
                (const __attribute__((address_space(1))) void*)(g0 + rd * 4096),
                (__attribute__((address_space(3))) void*)(l0 + rd * 4096),
                16, 0, 2 /* NT: single-use A stream */);
        }
    };

    auto aoff = [&](int buf, int row, int chunk)->int {
        return buf * TILEB + row * (RL * 2) + (((chunk) ^ (row & XM)) << 4);
    };

    bf8 bb[3][5];
    auto loadB = [&](int ks, int slot){
        #pragma unroll
        for (int n = 0; n < 5; n++)
            bb[slot][n] = *(const bf8*)(Wt + (long)(w * 80 + n * 16 + lr) * Ktot + ks * 32 + g * 8);
    };

    f4 acc[4][5];

    int tile = blockIdx.x;
    if (tile >= nTiles) return;
    dma(Ap[0], tile * 64, 0);
    __syncthreads();                       // drain prologue DMA

    int buf = 0;
    for (; tile < nTiles; tile += gridDim.x){
        #pragma unroll
        for (int m = 0; m < 4; m++)
            #pragma unroll
            for (int n = 0; n < 5; n++)
                acc[m][n] = (f4){0.f, 0.f, 0.f, 0.f};

        #pragma unroll
        for (int sec = 0; sec < SEC; ++sec){
            // issue next unit's DMA into the other buffer (overlaps compute)
            {
                int ns = sec + 1, ntile = tile;
                if (ns == SEC){ ns = 0; ntile = tile + (int)gridDim.x; }
                if (ntile < nTiles) dma(Ap[ns], ntile * 64, buf ^ 1);
            }
            loadB(sec * KS + 0, 0);
            loadB(sec * KS + 1, 1);
            loadB(sec * KS + 2, 2);

            #pragma unroll
            for (int i = 0; i < KS; i++){
                bf8 af[4];
                #pragma unroll
                for (int m = 0; m < 4; m++)
                    af[m] = *(const bf8*)(lds + aoff(buf, m * 16 + lr, i * 4 + g));
                // swapped operands: D^T -> lane holds row (lane&15), 4 cols
                #pragma unroll
                for (int m = 0; m < 4; m++)
                    #pragma unroll
                    for (int n = 0; n < 5; n++)
                        acc[m][n] = __builtin_amdgcn_mfma_f32_16x16x32_bf16(bb[i % 3][n], af[m], acc[m][n], 0, 0, 0);
                if (i + 3 < KS) loadB(sec * KS + i + 3, i % 3);
            }

            if (sec == SEC - 1){
                #pragma unroll
                for (int m = 0; m < 4; m++){
                    const long row = tile * 64 + m * 16 + lr;
                    const long rbase = row * HP;
                    const int rx = (int)row & 7;
                    #pragma unroll
                    for (int n = 0; n < 5; n++){
                        const int colBase = w * 80 + n * 16 + g * 4;
                        s4 v4;
                        #pragma unroll
                        for (int q = 0; q < 4; q++){
                            int col = colBase + q;
                            float v = acc[m][n][q];
                            if constexpr (EPI == 2) v += (col < H ? b_o[col] : 0.f);
                            if constexpr (EPI != 1) v = fmaxf(v, 0.f);
                            v4[q] = (short)f2bf(v);
                        }
                        int ch = colBase >> 3;
                        *(s4*)(outb + rbase + ((long)(ch ^ rx) << 3) + (colBase & 7)) = v4;
                    }
                }
            }
            __syncthreads();               // drain DMA(next) + LDS-read fence
            buf ^= 1;
        }
    }
}

// ---------------------------------------------------------------------------
// comb: msg'[e] = relu(bond_in[e] + sum_{j in bucket[src[e]]} MW[j] - MW[rev[e]])
// thread = (bond, 16B chunk); all buffers in swizzled layout.
// ---------------------------------------------------------------------------
__global__ __launch_bounds__(256)
void comb_k(const unsigned short* __restrict__ MW,
            const unsigned short* __restrict__ bond_in,
            const int* __restrict__ b_src, const int* __restrict__ b2revb,
            const int* __restrict__ cnt, const int* __restrict__ bucket,
            unsigned short* __restrict__ out, int nB){
    int t = blockIdx.x * 256 + threadIdx.x;
    if (t >= nB * 40) return;
    int e = t / 40, ch = t % 40;
    int s   = b_src[e];
    int rev = b2revb[e];
    int dg = cnt[s]; if (dg > CAP) dg = CAP;
    long base = (long)s * CAP;
    int be0 = 0, be1 = 0, be2 = 0, be3 = 0;
    if (dg > 0) be0 = bucket[base + 0];
    if (dg > 1) be1 = bucket[base + 1];
    if (dg > 2) be2 = bucket[base + 2];
    if (dg > 3) be3 = bucket[base + 3];
    bf8 bi = *(const bf8*)(bond_in + sidx320(e, ch));
    bf8 rv = *(const bf8*)(MW + sidx320(rev, ch));
    bf8 m0, m1, m2, m3;
    if (dg > 0) m0 = *(const bf8*)(MW + sidx320(be0, ch));
    if (dg > 1) m1 = *(const bf8*)(MW + sidx320(be1, ch));
    if (dg > 2) m2 = *(const bf8*)(MW + sidx320(be2, ch));
    if (dg > 3) m3 = *(const bf8*)(MW + sidx320(be3, ch));
    float sacc[8];
    #pragma unroll
    for (int q = 0; q < 8; q++)
        sacc[q] = bf2f((unsigned short)bi[q]) - bf2f((unsigned short)rv[q]);
    auto addv = [&](bf8 mm){
        #pragma unroll
        for (int q = 0; q < 8; q++) sacc[q] += bf2f((unsigned short)mm[q]);
    };
    if (dg > 0) addv(m0);
    if (dg > 1) addv(m1);
    if (dg > 2) addv(m2);
    if (dg > 3) addv(m3);
    for (int j = 4; j < dg; ++j){
        int be = bucket[base + j];
        addv(*(const bf8*)(MW + sidx320(be, ch)));
    }
    bf8 v;
    #pragma unroll
    for (int q = 0; q < 8; q++) v[q] = (short)f2bf(fmaxf(sacc[q], 0.f));
    *(bf8*)(out + sidx320(e, ch)) = v;
}

// ---------------------------------------------------------------------------
// a_msg[a] = sum of msg rows with dst==a; also prod[a] = a_msg[a] * input_atom[a]
// ---------------------------------------------------------------------------
__global__ __launch_bounds__(256)
void amsg_k(const unsigned short* __restrict__ msg, const int* __restrict__ cnt,
            const int* __restrict__ bucket,
            const unsigned short* __restrict__ input_atom,
            unsigned short* __restrict__ amsg, unsigned short* __restrict__ prod,
            int nA){
    int t = blockIdx.x * 256 + threadIdx.x;
    if (t >= nA * 40) return;
    int a = t / 40, ch = t % 40;
    int dg = cnt[a]; if (dg > CAP) dg = CAP;
    long base = (long)a * CAP;
    int be0 = 0, be1 = 0, be2 = 0, be3 = 0;
    if (dg > 0) be0 = bucket[base + 0];
    if (dg > 1) be1 = bucket[base + 1];
    if (dg > 2) be2 = bucket[base + 2];
    if (dg > 3) be3 = bucket[base + 3];
    bf8 ia = *(const bf8*)(input_atom + sidx320(a, ch));
    bf8 m0, m1, m2, m3;
    if (dg > 0) m0 = *(const bf8*)(msg + sidx320(be0, ch));
    if (dg > 1) m1 = *(const bf8*)(msg + sidx320(be1, ch));
    if (dg > 2) m2 = *(const bf8*)(msg + sidx320(be2, ch));
    if (dg > 3) m3 = *(const bf8*)(msg + sidx320(be3, ch));
    float s[8];
    #pragma unroll
    for (int q = 0; q < 8; q++) s[q] = 0.f;
    auto addv = [&](bf8 mm){
        #pragma unroll
        for (int q = 0; q < 8; q++) s[q] += bf2f((unsigned short)mm[q]);
    };
    if (dg > 0) addv(m0);
    if (dg > 1) addv(m1);
    if (dg > 2) addv(m2);
    if (dg > 3) addv(m3);
    for (int j = 4; j < dg; ++j)
        addv(*(const bf8*)(msg + sidx320(bucket[base + j], ch)));
    bf8 va, vp;
    #pragma unroll
    for (int q = 0; q < 8; q++){
        va[q] = (short)f2bf(s[q]);
        vp[q] = (short)f2bf(s[q] * bf2f((unsigned short)ia[q]));
    }
    *(bf8*)(amsg + sidx320(a, ch)) = va;
    *(bf8*)(prod + sidx320(a, ch)) = vp;
}

// ---------------------------------------------------------------------------
// Readout: per-molecule mean over sorted mol_ids (binary-search range).
// ---------------------------------------------------------------------------
__global__ __launch_bounds__(320)
void readout_k(const unsigned short* __restrict__ atom_h,
               const int* __restrict__ mol_ids, int nAtoms,
               float* __restrict__ out){
    int m = blockIdx.x;
    int t = threadIdx.x;
    int lo = 0, hi = nAtoms;
    while (lo < hi){ int mid = (lo + hi) >> 1; if (mol_ids[mid] < m) lo = mid + 1; else hi = mid; }
    int lo2 = lo, hi2 = nAtoms;
    while (lo2 < hi2){ int mid = (lo2 + hi2) >> 1; if (mol_ids[mid] < m + 1) lo2 = mid + 1; else hi2 = mid; }
    if (t < H){
        int ch = t >> 3, j = t & 7;
        float s = 0.f;
        for (int a = lo; a < lo2; ++a)
            s += bf2f(atom_h[sidx320(a, ch) + j]);
        int c2 = lo2 - lo;
        out[(long)m * H + t] = s / (float)(c2 > 0 ? c2 : 1);
    }
}

// ---------------------------------------------------------------------------
extern "C" void kernel_launch(void* const* d_in, const int* in_sizes, int n_in,
                              void* d_out, int out_size, void* d_ws, size_t ws_size,
                              hipStream_t stream){
    const float* f_atoms  = (const float*)d_in[0];
    const float* f_bonds  = (const float*)d_in[1];
    const float* W_i_atom = (const float*)d_in[2];
    const float* W_i_bond = (const float*)d_in[3];
    const float* W_h      = (const float*)d_in[4];
    const float* W_o      = (const float*)d_in[5];
    const float* b_o      = (const float*)d_in[6];
    const int* b_src   = (const int*)d_in[7];
    const int* b_dst   = (const int*)d_in[8];
    const int* b2revb  = (const int*)d_in[9];
    const int* mol_ids = (const int*)d_in[10];

    const int nA = in_sizes[10];          // 200000
    const int nB = in_sizes[7];           // 400000
    const int nM = out_size / H;          // 4096

    char* p = (char*)d_ws;
    auto alloc = [&](size_t bytes){ char* q = p; p += (bytes + 255) & ~(size_t)255; return q; };
    unsigned short* Wt_ia = (unsigned short*)alloc((size_t)320 * 160 * 2);
    unsigned short* Wt_ib = (unsigned short*)alloc((size_t)320 * 160 * 2);
    unsigned short* Wt_h  = (unsigned short*)alloc((size_t)3 * 320 * 320 * 2);
    unsigned short* Wt_o  = (unsigned short*)alloc((size_t)320 * 960 * 2);
    int* cnt    = (int*)alloc((size_t)nA * 4);
    int* bucket = (int*)alloc((size_t)nA * CAP * 4);
    unsigned short* input_atom = (unsigned short*)alloc((size_t)nA * HP * 2);
    unsigned short* input_bond = (unsigned short*)alloc((size_t)nB * HP * 2);
    unsigned short* msgA = (unsigned short*)alloc((size_t)nB * HP * 2);
    unsigned short* MW   = (unsigned short*)alloc((size_t)nB * HP * 2);
    // aliases into dead regions:
    unsigned short* fa_bf  = MW;                                  // [nA][160], dead before MW first written
    unsigned short* fb_bf  = MW + (size_t)nA * 160;               // [nB][160]
    unsigned short* amsg   = MW;                                  // MW dead after comb3
    unsigned short* prod   = MW + (size_t)nA * HP;
    unsigned short* atom_h = input_bond;                          // dead after comb3

    if ((size_t)(p - (char*)d_ws) > ws_size) return;  // diagnostic: ws too small

    // adjacency buckets
    hipMemsetAsync(cnt, 0, (size_t)nA * 4, stream);
    fill_k<<<dim3((nB + 255) / 256), dim3(256), 0, stream>>>(b_dst, cnt, bucket, nB);

    // weight prep + input conversion (inputs pre-swizzled)
    prep_wt<<<dim3((320*160 + 255)/256), dim3(256), 0, stream>>>(W_i_atom, Wt_ia, 133, 160);
    prep_wt<<<dim3((320*160 + 255)/256), dim3(256), 0, stream>>>(W_i_bond, Wt_ib, 147, 160);
    for (int d = 0; d < 3; d++)
        prep_wt<<<dim3((320*320 + 255)/256), dim3(256), 0, stream>>>(
            W_h + (size_t)d * H * H, Wt_h + (size_t)d * 320 * 320, 300, 320);
    prep_wto<<<dim3((320*960 + 255)/256), dim3(256), 0, stream>>>(W_o, Wt_o);
    conv_in<<<dim3((nA*20 + 255)/256), dim3(256), 0, stream>>>(f_atoms, nA, 133, fa_bf);
    conv_in<<<dim3((nB*20 + 255)/256), dim3(256), 0, stream>>>(f_bonds, nB, 147, fb_bf);

    const int tilesA = nA / 64, tilesB = nB / 64;

    // input projections
    gemm_p<160,1,0><<<dim3(1024), dim3(256), 0, stream>>>(
        fa_bf, nullptr, nullptr, Wt_ia, nullptr, input_atom, tilesA);
    gemm_p<160,1,0><<<dim3(1024), dim3(256), 0, stream>>>(
        fb_bf, nullptr, nullptr, Wt_ib, nullptr, input_bond, tilesB);

    // message steps: MW = msg @ W_h[d]; msg' = relu(bond_in + bucket-sum - rev)
    const int combGrid = (nB * 40 + 255) / 256;
    const unsigned short* msg_cur = input_bond;
    for (int d = 0; d < 3; d++){
        gemm_p<320,1,1><<<dim3(256), dim3(256), 0, stream>>>(
            msg_cur, nullptr, nullptr, Wt_h + (size_t)d * 320 * 320, nullptr, MW, tilesB);
        comb_k<<<dim3(combGrid), dim3(256), 0, stream>>>(
            MW, input_bond, b_src, b2revb, cnt, bucket, msgA, nB);
        msg_cur = msgA;
    }

    // final per-atom aggregation + product (bf16, swizzled)
    amsg_k<<<dim3((nA * 40 + 255) / 256), dim3(256), 0, stream>>>(
        msgA, cnt, bucket, input_atom, amsg, prod, nA);

    // atom_h = relu([input_atom | amsg | input_atom*amsg] @ W_o + b_o)
    gemm_p<320,3,2><<<dim3(256), dim3(256), 0, stream>>>(
        input_atom, amsg, prod, Wt_o, b_o, atom_h, tilesA);

    // per-molecule mean
    readout_k<<<dim3(nM), dim3(320), 0, stream>>>(atom_h, mol_ids, nA, (float*)d_out);
}